// Round 1
// baseline (3188.861 us; speedup 1.0000x reference)
//
#include <hip/hip_runtime.h>
#include <math.h>

// Problem constants (B=1)
#define PN 2048   // N tokens
#define PC 1024   // C channels
#define PH 8      // heads
#define PD 128    // head dim
#define PC3 3072  // 3*C

// ---------------- GEMM: C = alpha * A @ B^T (+bias) (+accum) ----------------
// A: [M,K] row-major stride lda ; B: [Nn,K] row-major stride ldb ; C: [M,Nn] stride ldc
// M,Nn multiples of 64; K multiple of 16; all pointers 16B aligned; lda/ldb/ldc %4==0.
constexpr int TS = 64, BKK = 16, LDP = BKK + 4; // LDS stride 20 floats -> 2-way bank alias only (free)

__global__ __launch_bounds__(256) void gemm_abt_k(
    const float* __restrict__ A, int lda,
    const float* __restrict__ B, int ldb,
    float* __restrict__ C, int ldc, int K,
    const float* __restrict__ bias, float alpha, int accum)
{
    __shared__ float As[TS][LDP];
    __shared__ float Bs[TS][LDP];
    const int tid = threadIdx.x;
    const int tx = tid & 15, ty = tid >> 4;
    const int lr = tid >> 2, lk = (tid & 3) * 4;
    const int row0 = blockIdx.y * TS, col0 = blockIdx.x * TS;
    const float* Ap = A + (size_t)(row0 + lr) * lda + lk;
    const float* Bp = B + (size_t)(col0 + lr) * ldb + lk;
    float acc[4][4] = {};
    for (int kt = 0; kt < K; kt += BKK) {
        float4 av = *(const float4*)(Ap + kt);
        float4 bv = *(const float4*)(Bp + kt);
        __syncthreads();
        *(float4*)&As[lr][lk] = av;
        *(float4*)&Bs[lr][lk] = bv;
        __syncthreads();
#pragma unroll
        for (int k4 = 0; k4 < BKK; k4 += 4) {
            float4 a4[4], b4[4];
#pragma unroll
            for (int i = 0; i < 4; ++i) a4[i] = *(const float4*)&As[ty + 16 * i][k4];
#pragma unroll
            for (int j = 0; j < 4; ++j) b4[j] = *(const float4*)&Bs[tx + 16 * j][k4];
#pragma unroll
            for (int i = 0; i < 4; ++i)
#pragma unroll
                for (int j = 0; j < 4; ++j)
                    acc[i][j] += a4[i].x * b4[j].x + a4[i].y * b4[j].y +
                                 a4[i].z * b4[j].z + a4[i].w * b4[j].w;
        }
    }
#pragma unroll
    for (int i = 0; i < 4; ++i) {
        const int r = row0 + ty + 16 * i;
#pragma unroll
        for (int j = 0; j < 4; ++j) {
            const int c = col0 + tx + 16 * j;
            float v = alpha * acc[i][j];
            if (bias) v += bias[c];
            float* p = C + (size_t)r * ldc + c;
            if (accum) v += *p;
            *p = v;
        }
    }
}

// ---------------- GEMM: C = alpha * A @ B ----------------
// A: [M,K] stride lda ; B: [K,Nn] stride ldb ; C: [M,Nn] stride ldc
__global__ __launch_bounds__(256) void gemm_ab_k(
    const float* __restrict__ A, int lda,
    const float* __restrict__ B, int ldb,
    float* __restrict__ C, int ldc, int K,
    float alpha)
{
    __shared__ float As[TS][LDP];
    __shared__ float Bs[BKK][TS];
    const int tid = threadIdx.x;
    const int tx = tid & 15, ty = tid >> 4;
    const int lr = tid >> 2, lk = (tid & 3) * 4;
    const int kr = tid >> 4, c4 = (tid & 15) * 4;
    const int row0 = blockIdx.y * TS, col0 = blockIdx.x * TS;
    const float* Ap = A + (size_t)(row0 + lr) * lda + lk;
    const float* Bp = B + col0 + c4;
    float acc[4][4] = {};
    for (int kt = 0; kt < K; kt += BKK) {
        float4 av = *(const float4*)(Ap + kt);
        float4 bv = *(const float4*)(Bp + (size_t)(kt + kr) * ldb);
        __syncthreads();
        *(float4*)&As[lr][lk] = av;
        *(float4*)&Bs[kr][c4] = bv;
        __syncthreads();
#pragma unroll
        for (int k4 = 0; k4 < BKK; k4 += 4) {
#pragma unroll
            for (int kk = 0; kk < 4; ++kk) {
                float a_[4];
#pragma unroll
                for (int i = 0; i < 4; ++i) a_[i] = As[ty + 16 * i][k4 + kk];
                float4 b4 = *(const float4*)&Bs[k4 + kk][tx * 4];
#pragma unroll
                for (int i = 0; i < 4; ++i) {
                    acc[i][0] += a_[i] * b4.x;
                    acc[i][1] += a_[i] * b4.y;
                    acc[i][2] += a_[i] * b4.z;
                    acc[i][3] += a_[i] * b4.w;
                }
            }
        }
    }
#pragma unroll
    for (int i = 0; i < 4; ++i) {
        const int r = row0 + ty + 16 * i;
        float4 v;
        v.x = alpha * acc[i][0];
        v.y = alpha * acc[i][1];
        v.z = alpha * acc[i][2];
        v.w = alpha * acc[i][3];
        *(float4*)(C + (size_t)r * ldc + col0 + tx * 4) = v;
    }
}

// ---------------- reductions ----------------
__device__ __forceinline__ float wave_sum(float v) {
#pragma unroll
    for (int o = 32; o > 0; o >>= 1) v += __shfl_xor(v, o, 64);
    return v;
}
__device__ __forceinline__ float wave_max(float v) {
#pragma unroll
    for (int o = 32; o > 0; o >>= 1) v = fmaxf(v, __shfl_xor(v, o, 64));
    return v;
}
// 256-thread block reductions; sm must be float[4]
__device__ __forceinline__ float block_sum(float v, float* sm) {
    v = wave_sum(v);
    __syncthreads();
    if ((threadIdx.x & 63) == 0) sm[threadIdx.x >> 6] = v;
    __syncthreads();
    return sm[0] + sm[1] + sm[2] + sm[3];
}
__device__ __forceinline__ float block_max(float v, float* sm) {
    v = wave_max(v);
    __syncthreads();
    if ((threadIdx.x & 63) == 0) sm[threadIdx.x >> 6] = v;
    __syncthreads();
    return fmaxf(fmaxf(sm[0], sm[1]), fmaxf(sm[2], sm[3]));
}

// ---------------- L2 normalization kernels ----------------
// normalize q (s=0) and k (s=1) sections of qkv [N,3C] in place, per (n,h) 128-vec
__global__ void norm_qk_k(float* __restrict__ qkv)
{
    const int n = blockIdx.x, s = blockIdx.y, h = blockIdx.z;
    float* p = qkv + (size_t)n * PC3 + s * PC + h * PD;
    const int t = threadIdx.x;
    float a = p[t], b = p[t + 64];
    float ss = wave_sum(a * a + b * b);
    float rn = rsqrtf(ss);
    p[t] = a * rn;
    p[t + 64] = b * rn;
}

// Vn = l2n(v_cls) per (n,h); also write x_ori half of trans_cls
__global__ void norm_v_k(const float* __restrict__ qkv_cls,
                         float* __restrict__ Vn, float* __restrict__ trans)
{
    const int n = blockIdx.x, h = blockIdx.y;
    const float* p = qkv_cls + (size_t)n * PC3 + 2 * PC + h * PD;
    const int t = threadIdx.x;
    float a = p[t], b = p[t + 64];
    float ss = wave_sum(a * a + b * b);
    float rn = rsqrtf(ss);
    Vn[(size_t)n * PC + h * PD + t] = a * rn;
    Vn[(size_t)n * PC + h * PD + t + 64] = b * rn;
    trans[(size_t)n * (2 * PC) + PC + h * PD + t] = a;
    trans[(size_t)n * (2 * PC) + PC + h * PD + t + 64] = b;
}

// ---------------- fused dual softmax + combine ----------------
// attn = 0.5*(softmax(P1*SCALE*cs[m]) + softmax(P2*SCALE*fs[m])) -> overwrite P1
// sim_attn += attn/H  (overwrite when first)
__global__ __launch_bounds__(256) void softmax_combine_k(
    float* __restrict__ P1, const float* __restrict__ P2,
    const float* __restrict__ cs, const float* __restrict__ fs,
    float* __restrict__ sim_attn, int first)
{
    __shared__ float sm[4];
    const size_t row = (size_t)blockIdx.x * PN;
    const int t = threadIdx.x;
    float s1[8], s2[8];
#pragma unroll
    for (int j = 0; j < 8; ++j) {
        const int m = t + 256 * j;
        s1[j] = P1[row + m] * (25.0f * cs[m]);
        s2[j] = P2[row + m] * (25.0f * fs[m]);
    }
    float mx1 = -1e30f, mx2 = -1e30f;
#pragma unroll
    for (int j = 0; j < 8; ++j) { mx1 = fmaxf(mx1, s1[j]); mx2 = fmaxf(mx2, s2[j]); }
    mx1 = block_max(mx1, sm);
    mx2 = block_max(mx2, sm);
    float sum1 = 0.f, sum2 = 0.f;
#pragma unroll
    for (int j = 0; j < 8; ++j) {
        s1[j] = __expf(s1[j] - mx1); sum1 += s1[j];
        s2[j] = __expf(s2[j] - mx2); sum2 += s2[j];
    }
    sum1 = block_sum(sum1, sm);
    sum2 = block_sum(sum2, sm);
    const float i1 = 0.5f / sum1, i2 = 0.5f / sum2;
#pragma unroll
    for (int j = 0; j < 8; ++j) {
        const int m = t + 256 * j;
        float a = s1[j] * i1 + s2[j] * i2;
        P1[row + m] = a;
        float prev = first ? 0.f : sim_attn[row + m];
        sim_attn[row + m] = prev + a * 0.125f;
    }
}

// ---------------- sim_round2: softmax, mask by sim_raw>0.75, renormalize ----------------
__global__ __launch_bounds__(256) void sim_round2_k(
    float* __restrict__ S, const float* __restrict__ Sraw)
{
    __shared__ float sm[4];
    const size_t row = (size_t)blockIdx.x * PN;
    const int t = threadIdx.x;
    float v[8];
    bool keep[8];
#pragma unroll
    for (int j = 0; j < 8; ++j) {
        const int m = t + 256 * j;
        v[j] = S[row + m];
        keep[j] = Sraw[row + m] > 0.75f;
    }
    float mx = -1e30f;
#pragma unroll
    for (int j = 0; j < 8; ++j) mx = fmaxf(mx, v[j]);
    mx = block_max(mx, sm);
    float sum = 0.f;
#pragma unroll
    for (int j = 0; j < 8; ++j) { v[j] = __expf(v[j] - mx); sum += v[j]; }
    sum = block_sum(sum, sm);
    const float inv = 1.0f / sum;
    float msum = 0.f;
#pragma unroll
    for (int j = 0; j < 8; ++j) { v[j] = keep[j] ? v[j] * inv : 0.f; msum += v[j]; }
    msum = block_sum(msum, sm);
    const float minv = 1.0f / msum;
#pragma unroll
    for (int j = 0; j < 8; ++j) {
        const int m = t + 256 * j;
        S[row + m] = v[j] * minv;
    }
}

// ---------------- host ----------------
extern "C" void kernel_launch(void* const* d_in, const int* in_sizes, int n_in,
                              void* d_out, int out_size, void* d_ws, size_t ws_size,
                              hipStream_t stream)
{
    (void)in_sizes; (void)n_in; (void)out_size; (void)ws_size;
    const float* x_cls = (const float*)d_in[0];
    const float* x_reg = (const float*)d_in[1];
    const float* cls_score = (const float*)d_in[2];
    const float* fg_score = (const float*)d_in[3];
    const float* Wqc = (const float*)d_in[4];
    const float* Wqr = (const float*)d_in[5];
    const float* W1 = (const float*)d_in[6];
    const float* b1 = (const float*)d_in[7];
    const float* W2 = (const float*)d_in[8];
    const float* b2 = (const float*)d_in[9];
    float* out = (float*)d_out;

    // workspace layout (floats) — total 44,040,192 floats = 168 MiB
    float* ws = (float*)d_ws;
    float* qkv_cls  = ws;                                  // [N,3C]
    float* qkv_reg  = qkv_cls  + (size_t)PN * PC3;         // [N,3C]
    float* Vn       = qkv_reg  + (size_t)PN * PC3;         // [N,C]
    float* P1       = Vn       + (size_t)PN * PC;          // [N,N]
    float* P2       = P1       + (size_t)PN * PN;          // [N,N]
    float* sim_raw  = P2       + (size_t)PN * PN;          // [N,N]
    float* sim_attn = sim_raw  + (size_t)PN * PN;          // [N,N]
    float* trans    = sim_attn + (size_t)PN * PN;          // [N,2C]
    float* ave      = trans    + (size_t)PN * 2 * PC;      // [N,4C]

    // 1) QKV projections: qkv = x @ W^T
    gemm_abt_k<<<dim3(PC3 / TS, PN / TS), 256, 0, stream>>>(
        x_cls, PC, Wqc, PC, qkv_cls, PC3, PC, nullptr, 1.0f, 0);
    gemm_abt_k<<<dim3(PC3 / TS, PN / TS), 256, 0, stream>>>(
        x_reg, PC, Wqr, PC, qkv_reg, PC3, PC, nullptr, 1.0f, 0);

    // 2) normalize q,k in place; Vn = l2n(v_cls); x_ori half of trans
    norm_qk_k<<<dim3(PN, 2, PH), 64, 0, stream>>>(qkv_cls);
    norm_qk_k<<<dim3(PN, 2, PH), 64, 0, stream>>>(qkv_reg);
    norm_v_k<<<dim3(PN, PH), 64, 0, stream>>>(qkv_cls, Vn, trans);

    // 3) per-head attention
    for (int h = 0; h < PH; ++h) {
        const float* qc = qkv_cls + h * PD;            // q_cls[h], lda=3C
        const float* kc = qkv_cls + PC + h * PD;       // k_cls[h]
        const float* qr = qkv_reg + h * PD;
        const float* kr = qkv_reg + PC + h * PD;
        const float* vh = qkv_cls + 2 * PC + h * PD;   // v_cls[h] (unnormalized)
        const float* vnh = Vn + h * PD;                // v_cls_n[h], lda=C

        // S_cls = q_cls @ k_cls^T ; S_reg = q_reg @ k_reg^T
        gemm_abt_k<<<dim3(PN / TS, PN / TS), 256, 0, stream>>>(
            qc, PC3, kc, PC3, P1, PN, PD, nullptr, 1.0f, 0);
        gemm_abt_k<<<dim3(PN / TS, PN / TS), 256, 0, stream>>>(
            qr, PC3, kr, PC3, P2, PN, PD, nullptr, 1.0f, 0);
        // sim_raw += (1/H) * Vn[h] @ Vn[h]^T
        gemm_abt_k<<<dim3(PN / TS, PN / TS), 256, 0, stream>>>(
            vnh, PC, vnh, PC, sim_raw, PN, PD, nullptr, 0.125f, h == 0 ? 0 : 1);
        // attn (into P1) + sim_attn accumulation
        softmax_combine_k<<<PN, 256, 0, stream>>>(P1, P2, cls_score, fg_score,
                                                  sim_attn, h == 0 ? 1 : 0);
        // x[:, h*D:(h+1)*D] = attn @ v_cls[h]  (into trans cols [0,C))
        gemm_ab_k<<<dim3(PD / TS, PN / TS), 256, 0, stream>>>(
            P1, PN, vh, PC3, trans + h * PD, 2 * PC, PN, 1.0f);
    }

    // 4) sim_round2 (in place on sim_attn)
    sim_round2_k<<<PN, 256, 0, stream>>>(sim_attn, sim_raw);

    // 5) msa/feat = trans @ W1^T + b1  -> ave cols [2C,4C)
    gemm_abt_k<<<dim3((2 * PC) / TS, PN / TS), 256, 0, stream>>>(
        trans, 2 * PC, W1, 2 * PC, ave + 2 * PC, 4 * PC, 2 * PC, b1, 1.0f, 0);

    // 6) soft_sim = sim_round2 @ feat -> ave cols [0,2C)
    gemm_ab_k<<<dim3((2 * PC) / TS, PN / TS), 256, 0, stream>>>(
        sim_attn, PN, ave + 2 * PC, 4 * PC, ave, 4 * PC, PN, 1.0f);

    // 7) out = ave @ W2^T + b2
    gemm_abt_k<<<dim3(PC / TS, PN / TS), 256, 0, stream>>>(
        ave, 4 * PC, W2, 4 * PC, out, PC, 4 * PC, b2, 1.0f, 0);
}

// Round 2
// 634.846 us; speedup vs baseline: 5.0230x; 5.0230x over previous
//
#include <hip/hip_runtime.h>
#include <math.h>

#define PN 2048
#define PC 1024
#define PH 8
#define PD 128
#define PC3 3072

typedef __bf16 bf16x8 __attribute__((ext_vector_type(8)));
typedef float  f32x4  __attribute__((ext_vector_type(4)));
typedef short  s8v    __attribute__((ext_vector_type(8)));
typedef short  s4v    __attribute__((ext_vector_type(4)));

__device__ __forceinline__ short f2bf(float x) {
    unsigned u = __float_as_uint(x);
    unsigned r = (u + 0x7fffu + ((u >> 16) & 1u)) >> 16;
    return (short)r;
}
__device__ __forceinline__ float bf2f(short s) {
    return __uint_as_float(((unsigned)(unsigned short)s) << 16);
}

#define LDS_DMA(g, l) __builtin_amdgcn_global_load_lds( \
    (const __attribute__((address_space(1))) void*)(g), \
    (__attribute__((address_space(3))) void*)(l), 16, 0, 0)

// ---------------- bf16 MFMA GEMM:  C = alpha * A @ B^T (+bias) ----------------
// A: [M,K] bf16 row-major lda ; B: [Nn,K] bf16 row-major ldb ; C: [M,Nn] (fp32 or bf16)
// M mult of 128, Nn mult of BN, K mult of 32; z-batched via element strides.
template<int BN, bool OBF16, bool BIAS>
__global__ __launch_bounds__(256) void mfma_gemm_k(
    const short* __restrict__ A, int lda, long zsa,
    const short* __restrict__ B, int ldb, long zsb,
    void* __restrict__ Cv, int ldc, long zsc,
    int K, float alpha, const float* __restrict__ bias)
{
    constexpr int NJ = BN / 32;           // b-frags per wave
    __shared__ short As[128 * 32];
    __shared__ short Bs[BN * 32];
    const int tid = threadIdx.x;
    const int wave = tid >> 6, lane = tid & 63;
    const int lrow = tid >> 2;            // 0..63 (staging row)
    const int lcol = (tid & 3) * 8;       // staging col (elements)
    const int z = blockIdx.z;
    A += (long)z * zsa;
    B += (long)z * zsb;
    const int row0 = blockIdx.y * 128, col0 = blockIdx.x * BN;
    const short* Ag = A + (long)(row0 + lrow) * lda + lcol;
    const short* Bg = B + (long)(col0 + lrow) * ldb + lcol;
    short* AsW0 = As + wave * 512;
    short* AsW1 = As + 2048 + wave * 512;
    short* BsW0 = Bs + wave * 512;
    short* BsW1 = Bs + 2048 + wave * 512; // used only when BN==128
    const int wr = (wave >> 1) * 64, wc = (wave & 1) * (BN / 2);
    const int m16 = lane & 15, q8 = (lane >> 4) * 8;

    f32x4 acc[4][NJ];
#pragma unroll
    for (int i = 0; i < 4; ++i)
#pragma unroll
        for (int j = 0; j < NJ; ++j) acc[i][j] = (f32x4){0.f, 0.f, 0.f, 0.f};

    for (int kt = 0; kt < K; kt += 32) {
        if (kt) __syncthreads();
        LDS_DMA(Ag + kt, AsW0);
        LDS_DMA(Ag + kt + 64 * (long)lda, AsW1);
        LDS_DMA(Bg + kt, BsW0);
        if (BN == 128) LDS_DMA(Bg + kt + 64 * (long)ldb, BsW1);
        __syncthreads();
        bf16x8 a[4], b[NJ];
#pragma unroll
        for (int i = 0; i < 4; ++i)
            a[i] = *(const bf16x8*)&As[(wr + i * 16 + m16) * 32 + q8];
#pragma unroll
        for (int j = 0; j < NJ; ++j)
            b[j] = *(const bf16x8*)&Bs[(wc + j * 16 + m16) * 32 + q8];
#pragma unroll
        for (int i = 0; i < 4; ++i)
#pragma unroll
            for (int j = 0; j < NJ; ++j)
                acc[i][j] = __builtin_amdgcn_mfma_f32_16x16x32_bf16(a[i], b[j], acc[i][j], 0, 0, 0);
    }

    const long cz = (long)z * zsc;
#pragma unroll
    for (int i = 0; i < 4; ++i) {
        const int r0 = row0 + wr + i * 16 + (lane >> 4) * 4;
#pragma unroll
        for (int j = 0; j < NJ; ++j) {
            const int c = col0 + wc + j * 16 + m16;
            const float bv = BIAS ? bias[c] : 0.0f;
#pragma unroll
            for (int t = 0; t < 4; ++t) {
                const float x = acc[i][j][t] * alpha + bv;
                const long off = cz + (long)(r0 + t) * ldc + c;
                if (OBF16) ((short*)Cv)[off] = f2bf(x);
                else       ((float*)Cv)[off] = x;
            }
        }
    }
}

// ---------------- fp32 -> bf16 convert ----------------
__global__ __launch_bounds__(256) void f2bf_k(const float* __restrict__ src,
                                              short* __restrict__ dst, int n4)
{
    const int i = blockIdx.x * 256 + threadIdx.x;
    if (i < n4) {
        float4 v = ((const float4*)src)[i];
        s4v o;
        o[0] = f2bf(v.x); o[1] = f2bf(v.y); o[2] = f2bf(v.z); o[3] = f2bf(v.w);
        ((s4v*)dst)[i] = o;
    }
}

// ---------------- bf16 tiled transpose: dst[c][r] = src[r][c] ----------------
__global__ __launch_bounds__(256) void transpose_bf16_k(
    const short* __restrict__ src, int sld, short* __restrict__ dst, int dld)
{
    __shared__ short tl[64][72];
    const int r0 = blockIdx.y * 64, c0 = blockIdx.x * 64;
    const int tr = threadIdx.x >> 2;
    const int tc = (threadIdx.x & 3) * 16;
    const short* sp = src + (long)(r0 + tr) * sld + c0 + tc;
    s8v v0 = *(const s8v*)sp;
    s8v v1 = *(const s8v*)(sp + 8);
    *(s8v*)&tl[tr][tc] = v0;
    *(s8v*)&tl[tr][tc + 8] = v1;
    __syncthreads();
    s8v o0, o1;
#pragma unroll
    for (int k = 0; k < 8; ++k) { o0[k] = tl[tc + k][tr]; o1[k] = tl[tc + 8 + k][tr]; }
    short* dp = dst + (long)(c0 + tr) * dld + r0 + tc;
    *(s8v*)dp = o0;
    *(s8v*)(dp + 8) = o1;
}

// ---------------- per-(row,head) L2 norm of q,k in place (bf16) ----------------
// grid (N, 2{q,k}, 2{cls,reg});  qkv buffers adjacent with stride PN*PC3
__global__ __launch_bounds__(256) void norm_qk_k(short* __restrict__ qkv)
{
    short* p = qkv + (long)blockIdx.z * ((long)PN * PC3)
                   + (long)blockIdx.x * PC3 + blockIdx.y * PC + threadIdx.x * 4;
    s4v v = *(s4v*)p;
    float f0 = bf2f(v[0]), f1 = bf2f(v[1]), f2 = bf2f(v[2]), f3 = bf2f(v[3]);
    float ss = f0 * f0 + f1 * f1 + f2 * f2 + f3 * f3;
    ss += __shfl_xor(ss, 16, 64); ss += __shfl_xor(ss, 8, 64);
    ss += __shfl_xor(ss, 4, 64);  ss += __shfl_xor(ss, 2, 64);
    ss += __shfl_xor(ss, 1, 64);
    const float rn = rsqrtf(ss);
    s4v o;
    o[0] = f2bf(f0 * rn); o[1] = f2bf(f1 * rn); o[2] = f2bf(f2 * rn); o[3] = f2bf(f3 * rn);
    *(s4v*)p = o;
}

// ---------------- v processing: Vn = l2n(v) per head; trans x_ori = raw v ----------------
__global__ __launch_bounds__(256) void norm_v_k(const short* __restrict__ qkv_cls,
                                                short* __restrict__ Vn,
                                                short* __restrict__ trans)
{
    const int n = blockIdx.x, t = threadIdx.x;
    const short* p = qkv_cls + (long)n * PC3 + 2 * PC + t * 4;
    s4v v = *(const s4v*)p;
    float f0 = bf2f(v[0]), f1 = bf2f(v[1]), f2 = bf2f(v[2]), f3 = bf2f(v[3]);
    float ss = f0 * f0 + f1 * f1 + f2 * f2 + f3 * f3;
    ss += __shfl_xor(ss, 16, 64); ss += __shfl_xor(ss, 8, 64);
    ss += __shfl_xor(ss, 4, 64);  ss += __shfl_xor(ss, 2, 64);
    ss += __shfl_xor(ss, 1, 64);
    const float rn = rsqrtf(ss);
    s4v o;
    o[0] = f2bf(f0 * rn); o[1] = f2bf(f1 * rn); o[2] = f2bf(f2 * rn); o[3] = f2bf(f3 * rn);
    *(s4v*)(Vn + (long)n * PC + t * 4) = o;
    *(s4v*)(trans + (long)n * (2 * PC) + PC + t * 4) = v;  // raw copy
}

// ---------------- reductions ----------------
__device__ __forceinline__ float wave_sum(float v) {
#pragma unroll
    for (int o = 32; o > 0; o >>= 1) v += __shfl_xor(v, o, 64);
    return v;
}
__device__ __forceinline__ float wave_max(float v) {
#pragma unroll
    for (int o = 32; o > 0; o >>= 1) v = fmaxf(v, __shfl_xor(v, o, 64));
    return v;
}
__device__ __forceinline__ float block_sum(float v, float* sm) {
    v = wave_sum(v);
    __syncthreads();
    if ((threadIdx.x & 63) == 0) sm[threadIdx.x >> 6] = v;
    __syncthreads();
    return sm[0] + sm[1] + sm[2] + sm[3];
}
__device__ __forceinline__ float block_max(float v, float* sm) {
    v = wave_max(v);
    __syncthreads();
    if ((threadIdx.x & 63) == 0) sm[threadIdx.x >> 6] = v;
    __syncthreads();
    return fmaxf(fmaxf(sm[0], sm[1]), fmaxf(sm[2], sm[3]));
}

// ---------------- fused dual softmax + combine (bf16 attn out) ----------------
__global__ __launch_bounds__(256) void softmax_combine_k(
    const float* __restrict__ P1, const float* __restrict__ P2,
    const float* __restrict__ cs, const float* __restrict__ fs,
    short* __restrict__ attn_out, float* __restrict__ sim_attn, int first)
{
    __shared__ float sm[4];
    const long row = (long)blockIdx.x * PN;
    const int t = threadIdx.x;
    float s1[8], s2[8];
#pragma unroll
    for (int j = 0; j < 8; ++j) {
        const int m = t + 256 * j;
        s1[j] = P1[row + m] * (25.0f * cs[m]);
        s2[j] = P2[row + m] * (25.0f * fs[m]);
    }
    float mx1 = -1e30f, mx2 = -1e30f;
#pragma unroll
    for (int j = 0; j < 8; ++j) { mx1 = fmaxf(mx1, s1[j]); mx2 = fmaxf(mx2, s2[j]); }
    mx1 = block_max(mx1, sm);
    mx2 = block_max(mx2, sm);
    float sum1 = 0.f, sum2 = 0.f;
#pragma unroll
    for (int j = 0; j < 8; ++j) {
        s1[j] = __expf(s1[j] - mx1); sum1 += s1[j];
        s2[j] = __expf(s2[j] - mx2); sum2 += s2[j];
    }
    sum1 = block_sum(sum1, sm);
    sum2 = block_sum(sum2, sm);
    const float i1 = 0.5f / sum1, i2 = 0.5f / sum2;
#pragma unroll
    for (int j = 0; j < 8; ++j) {
        const int m = t + 256 * j;
        const float a = s1[j] * i1 + s2[j] * i2;
        attn_out[row + m] = f2bf(a);
        const float prev = first ? 0.f : sim_attn[row + m];
        sim_attn[row + m] = prev + a * 0.125f;
    }
}

// ---------------- sim_round2: softmax, mask sim_raw>0.75, renorm, bf16 out ----------------
__global__ __launch_bounds__(256) void sim_round2_k(
    const float* __restrict__ S, const short* __restrict__ Sraw,
    short* __restrict__ Sout)
{
    __shared__ float sm[4];
    const long row = (long)blockIdx.x * PN;
    const int t = threadIdx.x;
    float v[8];
    bool keep[8];
#pragma unroll
    for (int j = 0; j < 8; ++j) {
        const int m = t + 256 * j;
        v[j] = S[row + m];
        keep[j] = bf2f(Sraw[row + m]) > 0.75f;
    }
    float mx = -1e30f;
#pragma unroll
    for (int j = 0; j < 8; ++j) mx = fmaxf(mx, v[j]);
    mx = block_max(mx, sm);
    float sum = 0.f;
#pragma unroll
    for (int j = 0; j < 8; ++j) { v[j] = __expf(v[j] - mx); sum += v[j]; }
    sum = block_sum(sum, sm);
    const float inv = 1.0f / sum;
    float msum = 0.f;
#pragma unroll
    for (int j = 0; j < 8; ++j) { v[j] = keep[j] ? v[j] * inv : 0.f; msum += v[j]; }
    msum = block_sum(msum, sm);
    const float minv = 1.0f / msum;
#pragma unroll
    for (int j = 0; j < 8; ++j) {
        const int m = t + 256 * j;
        Sout[row + m] = f2bf(v[j] * minv);
    }
}

// ---------------- host ----------------
extern "C" void kernel_launch(void* const* d_in, const int* in_sizes, int n_in,
                              void* d_out, int out_size, void* d_ws, size_t ws_size,
                              hipStream_t stream)
{
    (void)in_sizes; (void)n_in; (void)out_size; (void)ws_size;
    const float* x_cls = (const float*)d_in[0];
    const float* x_reg = (const float*)d_in[1];
    const float* cls_score = (const float*)d_in[2];
    const float* fg_score = (const float*)d_in[3];
    const float* Wqc = (const float*)d_in[4];
    const float* Wqr = (const float*)d_in[5];
    const float* W1 = (const float*)d_in[6];
    const float* b1 = (const float*)d_in[7];
    const float* W2 = (const float*)d_in[8];
    const float* b2 = (const float*)d_in[9];
    float* out = (float*)d_out;

    // ---- workspace layout (byte offsets in MiB), peak 160 MiB (<176 proven) ----
    char* w = (char*)d_ws;
    short* qkv_cls_bf = (short*)(w + ((size_t)0   << 20)); // 12 MiB [N,3C]
    short* qkv_reg_bf = (short*)(w + ((size_t)12  << 20)); // 12 MiB (adjacent: z-stride)
    float* P1         = (float*)(w + ((size_t)24  << 20)); // 16 MiB [N,N]
    float* P2         = (float*)(w + ((size_t)40  << 20)); // 16 MiB (adjacent)
    short* attn4      = (short*)(w + ((size_t)56  << 20)); // 32 MiB [4][N,N]
    float* sim_attn   = (float*)(w + ((size_t)88  << 20)); // 16 MiB
    short* sim_raw_bf = (short*)(w + ((size_t)104 << 20)); // 8 MiB
    short* Vn         = (short*)(w + ((size_t)112 << 20)); // 4 MiB [N,C]
    short* vT         = (short*)(w + ((size_t)116 << 20)); // 4 MiB [C,N] = [H][D][N]
    short* W1_bf      = (short*)(w + ((size_t)120 << 20)); // 8 MiB
    short* W2_bf      = (short*)(w + ((size_t)128 << 20)); // 8 MiB
    short* x_cls_bf   = (short*)(w + ((size_t)136 << 20)); // 4 MiB (dead after QKV)
    short* x_reg_bf   = (short*)(w + ((size_t)140 << 20)); // 4 MiB (dead after QKV)
    short* Wqc_bf     = (short*)(w + ((size_t)144 << 20)); // 6 MiB (dead after QKV)
    short* Wqr_bf     = (short*)(w + ((size_t)150 << 20)); // 6 MiB (dead after QKV)
    // overlays (written only after their underlying buffers are dead):
    short* trans      = (short*)(w + ((size_t)136 << 20)); // 8 MiB over x_*
    short* ave        = (short*)(w + ((size_t)144 << 20)); // 16 MiB over Wq*_bf (+4 fresh -> 160)
    short* sim_bf     = (short*)(w + ((size_t)24  << 20)); // 8 MiB over P1
    short* featT      = (short*)(w + ((size_t)40  << 20)); // 8 MiB over P2

    const long NN = (long)PN * PN;

    // ---- fp32 -> bf16 conversions ----
    f2bf_k<<<2048, 256, 0, stream>>>(x_cls, x_cls_bf, PN * PC / 4);
    f2bf_k<<<2048, 256, 0, stream>>>(x_reg, x_reg_bf, PN * PC / 4);
    f2bf_k<<<3072, 256, 0, stream>>>(Wqc, Wqc_bf, PC3 * PC / 4);
    f2bf_k<<<3072, 256, 0, stream>>>(Wqr, Wqr_bf, PC3 * PC / 4);
    f2bf_k<<<4096, 256, 0, stream>>>(W1, W1_bf, 2 * PC * 2 * PC / 4);
    f2bf_k<<<4096, 256, 0, stream>>>(W2, W2_bf, PC * 4 * PC / 4);

    // ---- QKV projections (bf16 out) ----
    mfma_gemm_k<128, true, false><<<dim3(24, 16, 1), 256, 0, stream>>>(
        x_cls_bf, PC, 0, Wqc_bf, PC, 0, qkv_cls_bf, PC3, 0, PC, 1.0f, nullptr);
    mfma_gemm_k<128, true, false><<<dim3(16, 16, 1), 256, 0, stream>>>(  // q,k only for reg
        x_reg_bf, PC, 0, Wqr_bf, PC, 0, qkv_reg_bf, PC3, 0, PC, 1.0f, nullptr);

    // ---- norms + v processing + v transpose ----
    norm_qk_k<<<dim3(PN, 2, 2), 256, 0, stream>>>(qkv_cls_bf);
    norm_v_k<<<dim3(PN), 256, 0, stream>>>(qkv_cls_bf, Vn, trans);
    transpose_bf16_k<<<dim3(PC / 64, PN / 64), 256, 0, stream>>>(
        qkv_cls_bf + 2 * PC, PC3, vT, PN);

    // ---- sim_raw = (Vn @ Vn^T)/H as ONE K=1024 GEMM (bf16 out) ----
    mfma_gemm_k<128, true, false><<<dim3(16, 16, 1), 256, 0, stream>>>(
        Vn, PC, 0, Vn, PC, 0, sim_raw_bf, PN, 0, PC, 0.125f, nullptr);

    // ---- per-head attention, 2 groups of 4 heads ----
    for (int g = 0; g < 2; ++g) {
        for (int hh = 0; hh < 4; ++hh) {
            const int h = g * 4 + hh;
            // z=0: cls -> P1 ; z=1: reg -> P2
            mfma_gemm_k<128, false, false><<<dim3(16, 16, 2), 256, 0, stream>>>(
                qkv_cls_bf + h * PD, PC3, (long)PN * PC3,
                qkv_cls_bf + PC + h * PD, PC3, (long)PN * PC3,
                P1, PN, NN, PD, 1.0f, nullptr);
            softmax_combine_k<<<PN, 256, 0, stream>>>(
                P1, P2, cls_score, fg_score, attn4 + (long)hh * NN, sim_attn, h == 0);
        }
        // x[:, (4g+z)*128 : +128] = attn_{4g+z} @ v_{4g+z}   (z = 0..3)
        mfma_gemm_k<64, true, false><<<dim3(2, 16, 4), 256, 0, stream>>>(
            attn4, PN, NN,
            vT + (long)g * 4 * PD * PN, PN, (long)PD * PN,
            trans + g * 4 * PD, 2 * PC, PD, PN, 1.0f, nullptr);
    }

    // ---- sim_round2 ----
    sim_round2_k<<<PN, 256, 0, stream>>>(sim_attn, sim_raw_bf, sim_bf);

    // ---- msa/feat = trans @ W1^T + b1 -> ave cols [2C,4C) (bf16) ----
    mfma_gemm_k<128, true, true><<<dim3(16, 16, 1), 256, 0, stream>>>(
        trans, 2 * PC, 0, W1_bf, 2 * PC, 0, ave + 2 * PC, 4 * PC, 0, 2 * PC, 1.0f, b1);

    // ---- featT = feat^T ----
    transpose_bf16_k<<<dim3(32, 32), 256, 0, stream>>>(ave + 2 * PC, 4 * PC, featT, 2 * PC);

    // ---- soft_sim = sim_round2 @ feat -> ave cols [0,2C) (bf16) ----
    mfma_gemm_k<128, true, false><<<dim3(16, 16, 1), 256, 0, stream>>>(
        sim_bf, 2 * PC, 0, featT, 2 * PC, 0, ave, 4 * PC, 0, 2 * PC, 1.0f, nullptr);

    // ---- out = ave @ W2^T + b2 (fp32 out) ----
    mfma_gemm_k<64, false, true><<<dim3(16, 16, 1), 256, 0, stream>>>(
        ave, 4 * PC, 0, W2_bf, 4 * PC, 0, out, PC, 0, 4 * PC, 1.0f, b2);
}

// Round 3
// 507.325 us; speedup vs baseline: 6.2856x; 1.2514x over previous
//
#include <hip/hip_runtime.h>
#include <math.h>

#define PN 2048
#define PC 1024
#define PH 8
#define PD 128
#define PC3 3072

typedef __bf16 bf16x8 __attribute__((ext_vector_type(8)));
typedef float  f32x4  __attribute__((ext_vector_type(4)));
typedef short  s8v    __attribute__((ext_vector_type(8)));
typedef short  s4v    __attribute__((ext_vector_type(4)));

__device__ __forceinline__ short f2bf(float x) {
    unsigned u = __float_as_uint(x);
    unsigned r = (u + 0x7fffu + ((u >> 16) & 1u)) >> 16;
    return (short)r;
}
__device__ __forceinline__ float bf2f(short s) {
    return __uint_as_float(((unsigned)(unsigned short)s) << 16);
}

#define LDS_DMA(g, l) __builtin_amdgcn_global_load_lds( \
    (const __attribute__((address_space(1))) void*)(g), \
    (__attribute__((address_space(3))) void*)(l), 16, 0, 0)

// stage a [128 rows][128 cols] bf16 tile (row stride ld) into LDS as 4 panels
// of [128][32] (panel kc at lds + kc*4096 shorts). 8 wave-linear DMAs.
__device__ __forceinline__ void stage128(const short* g, long ld, short* lds,
                                         int wave, int lrow, int lcol)
{
#pragma unroll
    for (int kc = 0; kc < 4; ++kc) {
        LDS_DMA(g + (long)lrow * ld + kc * 32 + lcol, lds + kc * 4096 + wave * 512);
        LDS_DMA(g + (long)(lrow + 64) * ld + kc * 32 + lcol,
                lds + kc * 4096 + 2048 + wave * 512);
    }
}

// ---------------- bf16 MFMA GEMM:  C = alpha * A @ B^T (+bias) ----------------
template<int BN, bool OBF16, bool BIAS>
__global__ __launch_bounds__(256) void mfma_gemm_k(
    const short* __restrict__ A, int lda, long zsa,
    const short* __restrict__ B, int ldb, long zsb,
    void* __restrict__ Cv, int ldc, long zsc,
    int K, float alpha, const float* __restrict__ bias)
{
    constexpr int NJ = BN / 32;
    __shared__ short As[128 * 32];
    __shared__ short Bs[BN * 32];
    const int tid = threadIdx.x;
    const int wave = tid >> 6, lane = tid & 63;
    const int lrow = tid >> 2;
    const int lcol = (tid & 3) * 8;
    const int z = blockIdx.z;
    A += (long)z * zsa;
    B += (long)z * zsb;
    const int row0 = blockIdx.y * 128, col0 = blockIdx.x * BN;
    const short* Ag = A + (long)(row0 + lrow) * lda + lcol;
    const short* Bg = B + (long)(col0 + lrow) * ldb + lcol;
    short* AsW0 = As + wave * 512;
    short* AsW1 = As + 2048 + wave * 512;
    short* BsW0 = Bs + wave * 512;
    short* BsW1 = Bs + 2048 + wave * 512;
    const int wr = (wave >> 1) * 64, wc = (wave & 1) * (BN / 2);
    const int m16 = lane & 15, q8 = (lane >> 4) * 8;

    f32x4 acc[4][NJ];
#pragma unroll
    for (int i = 0; i < 4; ++i)
#pragma unroll
        for (int j = 0; j < NJ; ++j) acc[i][j] = (f32x4){0.f, 0.f, 0.f, 0.f};

    for (int kt = 0; kt < K; kt += 32) {
        if (kt) __syncthreads();
        LDS_DMA(Ag + kt, AsW0);
        LDS_DMA(Ag + kt + 64 * (long)lda, AsW1);
        LDS_DMA(Bg + kt, BsW0);
        if (BN == 128) LDS_DMA(Bg + kt + 64 * (long)ldb, BsW1);
        __syncthreads();
        bf16x8 a[4], b[NJ];
#pragma unroll
        for (int i = 0; i < 4; ++i)
            a[i] = *(const bf16x8*)&As[(wr + i * 16 + m16) * 32 + q8];
#pragma unroll
        for (int j = 0; j < NJ; ++j)
            b[j] = *(const bf16x8*)&Bs[(wc + j * 16 + m16) * 32 + q8];
#pragma unroll
        for (int i = 0; i < 4; ++i)
#pragma unroll
            for (int j = 0; j < NJ; ++j)
                acc[i][j] = __builtin_amdgcn_mfma_f32_16x16x32_bf16(a[i], b[j], acc[i][j], 0, 0, 0);
    }

    const long cz = (long)z * zsc;
#pragma unroll
    for (int i = 0; i < 4; ++i) {
        const int r0 = row0 + wr + i * 16 + (lane >> 4) * 4;
#pragma unroll
        for (int j = 0; j < NJ; ++j) {
            const int c = col0 + wc + j * 16 + m16;
            const float bv = BIAS ? bias[c] : 0.0f;
#pragma unroll
            for (int t = 0; t < 4; ++t) {
                const float x = acc[i][j][t] * alpha + bv;
                const long off = cz + (long)(r0 + t) * ldc + c;
                if (OBF16) ((short*)Cv)[off] = f2bf(x);
                else       ((float*)Cv)[off] = x;
            }
        }
    }
}

// ---------------- attention kernel A: softmax row sums (no max needed) ----------------
// l_g[side][h][n] = sum_m exp( (q_n . k_m) * 25 * sc[m] )
__global__ __launch_bounds__(256) void attn_rowsum_k(
    const short* __restrict__ qkv,
    const float* __restrict__ cls_score, const float* __restrict__ fg_score,
    float* __restrict__ l_g)
{
    __shared__ short Qs[16384];
    __shared__ short Ks[2][16384];
    __shared__ float lsum[128][2];
    const int tid = threadIdx.x, wave = tid >> 6, lane = tid & 63;
    const int lrow = tid >> 2, lcol = (tid & 3) * 8;
    const int wr = (wave >> 1) * 64, wc = (wave & 1) * 64;
    const int m16 = lane & 15, q4 = lane >> 4, q8 = q4 * 8;
    const int row0 = blockIdx.x * 128, h = blockIdx.y, side = blockIdx.z;
    const float* sc_g = side ? fg_score : cls_score;
    const short* base = qkv + (long)side * PN * PC3 + h * PD;
    const short* Kg = base + PC;
    stage128(base + (long)row0 * PC3, PC3, Qs, wave, lrow, lcol);
    stage128(Kg, PC3, Ks[0], wave, lrow, lcol);
    bf16x8 a[4][4];
    float rs[4][4] = {};
    for (int ct = 0; ct < 16; ++ct) {
        __syncthreads();
        if (ct == 0) {
#pragma unroll
            for (int i = 0; i < 4; ++i)
#pragma unroll
                for (int kc = 0; kc < 4; ++kc)
                    a[i][kc] = *(const bf16x8*)&Qs[kc * 4096 + (wr + i * 16 + m16) * 32 + q8];
        }
        if (ct < 15)
            stage128(Kg + (long)(ct + 1) * 128 * PC3, PC3, Ks[(ct + 1) & 1], wave, lrow, lcol);
        const short* kb = Ks[ct & 1];
        f32x4 acc[4][4];
#pragma unroll
        for (int i = 0; i < 4; ++i)
#pragma unroll
            for (int j = 0; j < 4; ++j) acc[i][j] = (f32x4){0.f, 0.f, 0.f, 0.f};
#pragma unroll
        for (int kc = 0; kc < 4; ++kc) {
            bf16x8 b[4];
#pragma unroll
            for (int j = 0; j < 4; ++j)
                b[j] = *(const bf16x8*)&kb[kc * 4096 + (wc + j * 16 + m16) * 32 + q8];
#pragma unroll
            for (int i = 0; i < 4; ++i)
#pragma unroll
                for (int j = 0; j < 4; ++j)
                    acc[i][j] = __builtin_amdgcn_mfma_f32_16x16x32_bf16(a[i][kc], b[j], acc[i][j], 0, 0, 0);
        }
#pragma unroll
        for (int j = 0; j < 4; ++j) {
            const float s25 = 25.0f * sc_g[ct * 128 + wc + j * 16 + m16];
#pragma unroll
            for (int i = 0; i < 4; ++i)
#pragma unroll
                for (int t = 0; t < 4; ++t)
                    rs[i][t] += __expf(acc[i][j][t] * s25);
        }
    }
#pragma unroll
    for (int i = 0; i < 4; ++i)
#pragma unroll
        for (int t = 0; t < 4; ++t) {
            float v = rs[i][t];
            v += __shfl_xor(v, 1, 64); v += __shfl_xor(v, 2, 64);
            v += __shfl_xor(v, 4, 64); v += __shfl_xor(v, 8, 64);
            if (m16 == 0) lsum[wr + i * 16 + q4 * 4 + t][wave & 1] = v;
        }
    __syncthreads();
    if (tid < 128)
        l_g[((long)side * PH + h) * PN + row0 + tid] = lsum[tid][0] + lsum[tid][1];
}

// ---------------- attention kernel B: attn tiles + sim_attn ----------------
// attn8[h] tile = 0.5*(exp(s_cls)/l1 + exp(s_reg)/l2)  (bf16)
// sim_attn tile = sum_h attn8[h]/8  (fp32)
__global__ __launch_bounds__(256) void attn_combine_k(
    const short* __restrict__ qkv,
    const float* __restrict__ cls_score, const float* __restrict__ fg_score,
    const float* __restrict__ l_g,
    short* __restrict__ attn8, float* __restrict__ sim_attn)
{
    __shared__ short Ts[65536];  // 2 x (Q 16384 + K 16384) shorts = 128 KiB
    const int tid = threadIdx.x, wave = tid >> 6, lane = tid & 63;
    const int lrow = tid >> 2, lcol = (tid & 3) * 8;
    const int wr = (wave >> 1) * 64, wc = (wave & 1) * 64;
    const int m16 = lane & 15, q4 = lane >> 4, q8 = q4 * 8;
    const int col0 = blockIdx.x * 128, row0 = blockIdx.y * 128;
    const long NN = (long)PN * PN;

    {   // stage step 0 (h=0, s=0)
        const short* b0 = qkv;
        stage128(b0 + (long)row0 * PC3, PC3, Ts, wave, lrow, lcol);
        stage128(b0 + PC + (long)col0 * PC3, PC3, Ts + 16384, wave, lrow, lcol);
    }

    f32x4 sim[4][4];
#pragma unroll
    for (int i = 0; i < 4; ++i)
#pragma unroll
        for (int j = 0; j < 4; ++j) sim[i][j] = (f32x4){0.f, 0.f, 0.f, 0.f};
    f32x4 comb[4][4];

    for (int st = 0; st < 16; ++st) {
        const int h = st >> 1, s = st & 1;
        __syncthreads();
        if (st < 15) {
            const int h2 = (st + 1) >> 1, s2 = (st + 1) & 1;
            const short* b2 = qkv + (long)s2 * PN * PC3 + h2 * PD;
            short* dst = Ts + ((st + 1) & 1) * 32768;
            stage128(b2 + (long)row0 * PC3, PC3, dst, wave, lrow, lcol);
            stage128(b2 + PC + (long)col0 * PC3, PC3, dst + 16384, wave, lrow, lcol);
        }
        const short* Qb = Ts + (st & 1) * 32768;
        const short* Kb = Qb + 16384;

        float rl[4][4];
#pragma unroll
        for (int i = 0; i < 4; ++i)
#pragma unroll
            for (int t = 0; t < 4; ++t)
                rl[i][t] = 0.5f / l_g[((long)s * PH + h) * PN + row0 + wr + i * 16 + q4 * 4 + t];

        f32x4 acc[4][4];
#pragma unroll
        for (int i = 0; i < 4; ++i)
#pragma unroll
            for (int j = 0; j < 4; ++j) acc[i][j] = (f32x4){0.f, 0.f, 0.f, 0.f};
#pragma unroll
        for (int kc = 0; kc < 4; ++kc) {
            bf16x8 a[4], b[4];
#pragma unroll
            for (int i = 0; i < 4; ++i)
                a[i] = *(const bf16x8*)&Qb[kc * 4096 + (wr + i * 16 + m16) * 32 + q8];
#pragma unroll
            for (int j = 0; j < 4; ++j)
                b[j] = *(const bf16x8*)&Kb[kc * 4096 + (wc + j * 16 + m16) * 32 + q8];
#pragma unroll
            for (int i = 0; i < 4; ++i)
#pragma unroll
                for (int j = 0; j < 4; ++j)
                    acc[i][j] = __builtin_amdgcn_mfma_f32_16x16x32_bf16(a[i], b[j], acc[i][j], 0, 0, 0);
        }
        const float* sc_g = s ? fg_score : cls_score;
#pragma unroll
        for (int j = 0; j < 4; ++j) {
            const float s25 = 25.0f * sc_g[col0 + wc + j * 16 + m16];
#pragma unroll
            for (int i = 0; i < 4; ++i)
#pragma unroll
                for (int t = 0; t < 4; ++t) {
                    const float e = __expf(acc[i][j][t] * s25) * rl[i][t];
                    comb[i][j][t] = s ? (comb[i][j][t] + e) : e;
                }
        }
        if (s) {
#pragma unroll
            for (int i = 0; i < 4; ++i)
#pragma unroll
                for (int t = 0; t < 4; ++t) {
                    const long rbase = (long)h * NN +
                        (long)(row0 + wr + i * 16 + q4 * 4 + t) * PN + col0 + wc + m16;
#pragma unroll
                    for (int j = 0; j < 4; ++j)
                        attn8[rbase + j * 16] = f2bf(comb[i][j][t]);
                }
#pragma unroll
            for (int i = 0; i < 4; ++i)
#pragma unroll
                for (int j = 0; j < 4; ++j)
#pragma unroll
                    for (int t = 0; t < 4; ++t)
                        sim[i][j][t] += comb[i][j][t] * 0.125f;
        }
    }
#pragma unroll
    for (int i = 0; i < 4; ++i)
#pragma unroll
        for (int t = 0; t < 4; ++t) {
            const long rbase = (long)(row0 + wr + i * 16 + q4 * 4 + t) * PN + col0 + wc + m16;
#pragma unroll
            for (int j = 0; j < 4; ++j)
                sim_attn[rbase + j * 16] = sim[i][j][t];
        }
}

// ---------------- fp32 -> bf16 convert ----------------
__global__ __launch_bounds__(256) void f2bf_k(const float* __restrict__ src,
                                              short* __restrict__ dst, int n4)
{
    const int i = blockIdx.x * 256 + threadIdx.x;
    if (i < n4) {
        float4 v = ((const float4*)src)[i];
        s4v o;
        o[0] = f2bf(v.x); o[1] = f2bf(v.y); o[2] = f2bf(v.z); o[3] = f2bf(v.w);
        ((s4v*)dst)[i] = o;
    }
}

// ---------------- bf16 tiled transpose ----------------
__global__ __launch_bounds__(256) void transpose_bf16_k(
    const short* __restrict__ src, int sld, short* __restrict__ dst, int dld)
{
    __shared__ short tl[64][72];
    const int r0 = blockIdx.y * 64, c0 = blockIdx.x * 64;
    const int tr = threadIdx.x >> 2;
    const int tc = (threadIdx.x & 3) * 16;
    const short* sp = src + (long)(r0 + tr) * sld + c0 + tc;
    s8v v0 = *(const s8v*)sp;
    s8v v1 = *(const s8v*)(sp + 8);
    *(s8v*)&tl[tr][tc] = v0;
    *(s8v*)&tl[tr][tc + 8] = v1;
    __syncthreads();
    s8v o0, o1;
#pragma unroll
    for (int k = 0; k < 8; ++k) { o0[k] = tl[tc + k][tr]; o1[k] = tl[tc + 8 + k][tr]; }
    short* dp = dst + (long)(c0 + tr) * dld + r0 + tc;
    *(s8v*)dp = o0;
    *(s8v*)(dp + 8) = o1;
}

// ---------------- L2 norms ----------------
__global__ __launch_bounds__(256) void norm_qk_k(short* __restrict__ qkv)
{
    short* p = qkv + (long)blockIdx.z * ((long)PN * PC3)
                   + (long)blockIdx.x * PC3 + blockIdx.y * PC + threadIdx.x * 4;
    s4v v = *(s4v*)p;
    float f0 = bf2f(v[0]), f1 = bf2f(v[1]), f2 = bf2f(v[2]), f3 = bf2f(v[3]);
    float ss = f0 * f0 + f1 * f1 + f2 * f2 + f3 * f3;
    ss += __shfl_xor(ss, 16, 64); ss += __shfl_xor(ss, 8, 64);
    ss += __shfl_xor(ss, 4, 64);  ss += __shfl_xor(ss, 2, 64);
    ss += __shfl_xor(ss, 1, 64);
    const float rn = rsqrtf(ss);
    s4v o;
    o[0] = f2bf(f0 * rn); o[1] = f2bf(f1 * rn); o[2] = f2bf(f2 * rn); o[3] = f2bf(f3 * rn);
    *(s4v*)p = o;
}

__global__ __launch_bounds__(256) void norm_v_k(const short* __restrict__ qkv_cls,
                                                short* __restrict__ Vn,
                                                short* __restrict__ trans)
{
    const int n = blockIdx.x, t = threadIdx.x;
    const short* p = qkv_cls + (long)n * PC3 + 2 * PC + t * 4;
    s4v v = *(const s4v*)p;
    float f0 = bf2f(v[0]), f1 = bf2f(v[1]), f2 = bf2f(v[2]), f3 = bf2f(v[3]);
    float ss = f0 * f0 + f1 * f1 + f2 * f2 + f3 * f3;
    ss += __shfl_xor(ss, 16, 64); ss += __shfl_xor(ss, 8, 64);
    ss += __shfl_xor(ss, 4, 64);  ss += __shfl_xor(ss, 2, 64);
    ss += __shfl_xor(ss, 1, 64);
    const float rn = rsqrtf(ss);
    s4v o;
    o[0] = f2bf(f0 * rn); o[1] = f2bf(f1 * rn); o[2] = f2bf(f2 * rn); o[3] = f2bf(f3 * rn);
    *(s4v*)(Vn + (long)n * PC + t * 4) = o;
    *(s4v*)(trans + (long)n * (2 * PC) + PC + t * 4) = v;
}

// ---------------- reductions ----------------
__device__ __forceinline__ float wave_sum(float v) {
#pragma unroll
    for (int o = 32; o > 0; o >>= 1) v += __shfl_xor(v, o, 64);
    return v;
}
__device__ __forceinline__ float wave_max(float v) {
#pragma unroll
    for (int o = 32; o > 0; o >>= 1) v = fmaxf(v, __shfl_xor(v, o, 64));
    return v;
}
__device__ __forceinline__ float block_sum(float v, float* sm) {
    v = wave_sum(v);
    __syncthreads();
    if ((threadIdx.x & 63) == 0) sm[threadIdx.x >> 6] = v;
    __syncthreads();
    return sm[0] + sm[1] + sm[2] + sm[3];
}
__device__ __forceinline__ float block_max(float v, float* sm) {
    v = wave_max(v);
    __syncthreads();
    if ((threadIdx.x & 63) == 0) sm[threadIdx.x >> 6] = v;
    __syncthreads();
    return fmaxf(fmaxf(sm[0], sm[1]), fmaxf(sm[2], sm[3]));
}

// ---------------- sim_round2 ----------------
__global__ __launch_bounds__(256) void sim_round2_k(
    const float* __restrict__ S, const short* __restrict__ Sraw,
    short* __restrict__ Sout)
{
    __shared__ float sm[4];
    const long row = (long)blockIdx.x * PN;
    const int t = threadIdx.x;
    float v[8];
    bool keep[8];
#pragma unroll
    for (int j = 0; j < 8; ++j) {
        const int m = t + 256 * j;
        v[j] = S[row + m];
        keep[j] = bf2f(Sraw[row + m]) > 0.75f;
    }
    float mx = -1e30f;
#pragma unroll
    for (int j = 0; j < 8; ++j) mx = fmaxf(mx, v[j]);
    mx = block_max(mx, sm);
    float sum = 0.f;
#pragma unroll
    for (int j = 0; j < 8; ++j) { v[j] = __expf(v[j] - mx); sum += v[j]; }
    sum = block_sum(sum, sm);
    const float inv = 1.0f / sum;
    float msum = 0.f;
#pragma unroll
    for (int j = 0; j < 8; ++j) { v[j] = keep[j] ? v[j] * inv : 0.f; msum += v[j]; }
    msum = block_sum(msum, sm);
    const float minv = 1.0f / msum;
#pragma unroll
    for (int j = 0; j < 8; ++j) {
        const int m = t + 256 * j;
        Sout[row + m] = f2bf(v[j] * minv);
    }
}

// ---------------- host ----------------
extern "C" void kernel_launch(void* const* d_in, const int* in_sizes, int n_in,
                              void* d_out, int out_size, void* d_ws, size_t ws_size,
                              hipStream_t stream)
{
    (void)in_sizes; (void)n_in; (void)out_size; (void)ws_size;
    const float* x_cls = (const float*)d_in[0];
    const float* x_reg = (const float*)d_in[1];
    const float* cls_score = (const float*)d_in[2];
    const float* fg_score = (const float*)d_in[3];
    const float* Wqc = (const float*)d_in[4];
    const float* Wqr = (const float*)d_in[5];
    const float* W1 = (const float*)d_in[6];
    const float* b1 = (const float*)d_in[7];
    const float* W2 = (const float*)d_in[8];
    const float* b2 = (const float*)d_in[9];
    float* out = (float*)d_out;

    // ---- workspace (MiB offsets), peak ~160.2 MiB ----
    char* w = (char*)d_ws;
    short* qkv_cls_bf = (short*)(w + ((size_t)0   << 20)); // 12 MiB [N,3C]
    short* qkv_reg_bf = (short*)(w + ((size_t)12  << 20)); // 12 MiB (adjacent)
    short* attn8      = (short*)(w + ((size_t)24  << 20)); // 64 MiB [8][N][N] bf16
    float* sim_attn   = (float*)(w + ((size_t)88  << 20)); // 16 MiB
    short* sim_raw_bf = (short*)(w + ((size_t)104 << 20)); // 8 MiB
    short* Vn         = (short*)(w + ((size_t)112 << 20)); // 4 MiB
    short* vT         = (short*)(w + ((size_t)116 << 20)); // 4 MiB [C,N]
    short* W1_bf      = (short*)(w + ((size_t)120 << 20)); // 8 MiB
    short* W2_bf      = (short*)(w + ((size_t)128 << 20)); // 8 MiB
    short* x_cls_bf   = (short*)(w + ((size_t)136 << 20)); // 4 MiB (dead after QKV)
    short* x_reg_bf   = (short*)(w + ((size_t)140 << 20)); // 4 MiB (dead after QKV)
    short* Wqc_bf     = (short*)(w + ((size_t)144 << 20)); // 6 MiB (dead after QKV)
    short* Wqr_bf     = (short*)(w + ((size_t)150 << 20)); // 6 MiB (dead after QKV)
    float* l_g        = (float*)(w + ((size_t)160 << 20)); // 128 KiB [2][8][N]
    // overlays (after underlying dead):
    short* trans      = (short*)(w + ((size_t)136 << 20)); // 8 MiB over x_* (post-QKV)
    short* ave        = (short*)(w + ((size_t)144 << 20)); // 16 MiB over Wq*_bf
    short* sim_bf     = (short*)(w + ((size_t)24  << 20)); // 8 MiB over attn8[0] (post attn@V)
    short* featT      = (short*)(w + ((size_t)32  << 20)); // 8 MiB over attn8[1]

    const long NN = (long)PN * PN;

    // ---- fp32 -> bf16 ----
    f2bf_k<<<2048, 256, 0, stream>>>(x_cls, x_cls_bf, PN * PC / 4);
    f2bf_k<<<2048, 256, 0, stream>>>(x_reg, x_reg_bf, PN * PC / 4);
    f2bf_k<<<3072, 256, 0, stream>>>(Wqc, Wqc_bf, PC3 * PC / 4);
    f2bf_k<<<3072, 256, 0, stream>>>(Wqr, Wqr_bf, PC3 * PC / 4);
    f2bf_k<<<4096, 256, 0, stream>>>(W1, W1_bf, 2 * PC * 2 * PC / 4);
    f2bf_k<<<4096, 256, 0, stream>>>(W2, W2_bf, PC * 4 * PC / 4);

    // ---- QKV projections ----
    mfma_gemm_k<128, true, false><<<dim3(24, 16, 1), 256, 0, stream>>>(
        x_cls_bf, PC, 0, Wqc_bf, PC, 0, qkv_cls_bf, PC3, 0, PC, 1.0f, nullptr);
    mfma_gemm_k<128, true, false><<<dim3(16, 16, 1), 256, 0, stream>>>(  // q,k only
        x_reg_bf, PC, 0, Wqr_bf, PC, 0, qkv_reg_bf, PC3, 0, PC, 1.0f, nullptr);

    // ---- norms, v processing, v transpose ----
    norm_qk_k<<<dim3(PN, 2, 2), 256, 0, stream>>>(qkv_cls_bf);
    norm_v_k<<<dim3(PN), 256, 0, stream>>>(qkv_cls_bf, Vn, trans);
    transpose_bf16_k<<<dim3(PC / 64, PN / 64), 256, 0, stream>>>(
        qkv_cls_bf + 2 * PC, PC3, vT, PN);

    // ---- sim_raw = (Vn @ Vn^T)/H, one K=1024 GEMM ----
    mfma_gemm_k<128, true, false><<<dim3(16, 16, 1), 256, 0, stream>>>(
        Vn, PC, 0, Vn, PC, 0, sim_raw_bf, PN, 0, PC, 0.125f, nullptr);

    // ---- fused attention: row sums, then attn+sim tiles ----
    attn_rowsum_k<<<dim3(16, PH, 2), 256, 0, stream>>>(
        qkv_cls_bf, cls_score, fg_score, l_g);
    attn_combine_k<<<dim3(16, 16), 256, 0, stream>>>(
        qkv_cls_bf, cls_score, fg_score, l_g, attn8, sim_attn);

    // ---- x = attn @ v, all 8 heads in one z-batched dispatch ----
    mfma_gemm_k<64, true, false><<<dim3(2, 16, PH), 256, 0, stream>>>(
        attn8, PN, NN, vT, PN, (long)PD * PN, trans, 2 * PC, PD, PN, 1.0f, nullptr);

    // ---- sim_round2 ----
    sim_round2_k<<<PN, 256, 0, stream>>>(sim_attn, sim_raw_bf, sim_bf);

    // ---- msa/feat = trans @ W1^T + b1 ----
    mfma_gemm_k<128, true, true><<<dim3(16, 16, 1), 256, 0, stream>>>(
        trans, 2 * PC, 0, W1_bf, 2 * PC, 0, ave + 2 * PC, 4 * PC, 0, 2 * PC, 1.0f, b1);

    // ---- featT = feat^T ----
    transpose_bf16_k<<<dim3(32, 32), 256, 0, stream>>>(ave + 2 * PC, 4 * PC, featT, 2 * PC);

    // ---- soft_sim = sim_round2 @ feat ----
    mfma_gemm_k<128, true, false><<<dim3(16, 16, 1), 256, 0, stream>>>(
        sim_bf, 2 * PC, 0, featT, 2 * PC, 0, ave, 4 * PC, 0, 2 * PC, 1.0f, nullptr);

    // ---- out = ave @ W2^T + b2 ----
    mfma_gemm_k<64, false, true><<<dim3(16, 16, 1), 256, 0, stream>>>(
        ave, 4 * PC, 0, W2_bf, 4 * PC, 0, out, PC, 0, 4 * PC, 1.0f, b2);
}

// Round 5
// 504.063 us; speedup vs baseline: 6.3263x; 1.0065x over previous
//
#include <hip/hip_runtime.h>
#include <math.h>

#define PN 2048
#define PC 1024
#define PH 8
#define PD 128
#define PC3 3072

typedef __bf16 bf16x8 __attribute__((ext_vector_type(8)));
typedef float  f32x4  __attribute__((ext_vector_type(4)));
typedef short  s8v    __attribute__((ext_vector_type(8)));
typedef short  s4v    __attribute__((ext_vector_type(4)));

__device__ __forceinline__ short f2bf(float x) {
    unsigned u = __float_as_uint(x);
    unsigned r = (u + 0x7fffu + ((u >> 16) & 1u)) >> 16;
    return (short)r;
}
__device__ __forceinline__ float bf2f(short s) {
    return __uint_as_float(((unsigned)(unsigned short)s) << 16);
}

#define LDS_DMA(g, l) __builtin_amdgcn_global_load_lds( \
    (const __attribute__((address_space(1))) void*)(g), \
    (__attribute__((address_space(3))) void*)(l), 16, 0, 0)

// stage a [128 rows][128 cols] bf16 tile (row stride ld) into LDS as 4 panels
// of [128][32] (panel kc at lds + kc*4096 shorts). 8 wave-linear DMAs.
__device__ __forceinline__ void stage128(const short* g, long ld, short* lds,
                                         int wave, int lrow, int lcol)
{
#pragma unroll
    for (int kc = 0; kc < 4; ++kc) {
        LDS_DMA(g + (long)lrow * ld + kc * 32 + lcol, lds + kc * 4096 + wave * 512);
        LDS_DMA(g + (long)(lrow + 64) * ld + kc * 32 + lcol,
                lds + kc * 4096 + 2048 + wave * 512);
    }
}

// ---------------- bf16 MFMA GEMM:  C = alpha * A @ B^T (+bias) ----------------
template<int BN, bool OBF16, bool BIAS>
__global__ __launch_bounds__(256) void mfma_gemm_k(
    const short* __restrict__ A, int lda, long zsa,
    const short* __restrict__ B, int ldb, long zsb,
    void* __restrict__ Cv, int ldc, long zsc,
    int K, float alpha, const float* __restrict__ bias)
{
    constexpr int NJ = BN / 32;
    __shared__ short As[128 * 32];
    __shared__ short Bs[BN * 32];
    const int tid = threadIdx.x;
    const int wave = tid >> 6, lane = tid & 63;
    const int lrow = tid >> 2;
    const int lcol = (tid & 3) * 8;
    const int z = blockIdx.z;
    A += (long)z * zsa;
    B += (long)z * zsb;
    const int row0 = blockIdx.y * 128, col0 = blockIdx.x * BN;
    const short* Ag = A + (long)(row0 + lrow) * lda + lcol;
    const short* Bg = B + (long)(col0 + lrow) * ldb + lcol;
    short* AsW0 = As + wave * 512;
    short* AsW1 = As + 2048 + wave * 512;
    short* BsW0 = Bs + wave * 512;
    short* BsW1 = Bs + 2048 + wave * 512;
    const int wr = (wave >> 1) * 64, wc = (wave & 1) * (BN / 2);
    const int m16 = lane & 15, q8 = (lane >> 4) * 8;

    f32x4 acc[4][NJ];
#pragma unroll
    for (int i = 0; i < 4; ++i)
#pragma unroll
        for (int j = 0; j < NJ; ++j) acc[i][j] = (f32x4){0.f, 0.f, 0.f, 0.f};

    for (int kt = 0; kt < K; kt += 32) {
        if (kt) __syncthreads();
        LDS_DMA(Ag + kt, AsW0);
        LDS_DMA(Ag + kt + 64 * (long)lda, AsW1);
        LDS_DMA(Bg + kt, BsW0);
        if (BN == 128) LDS_DMA(Bg + kt + 64 * (long)ldb, BsW1);
        __syncthreads();
        bf16x8 a[4], b[NJ];
#pragma unroll
        for (int i = 0; i < 4; ++i)
            a[i] = *(const bf16x8*)&As[(wr + i * 16 + m16) * 32 + q8];
#pragma unroll
        for (int j = 0; j < NJ; ++j)
            b[j] = *(const bf16x8*)&Bs[(wc + j * 16 + m16) * 32 + q8];
#pragma unroll
        for (int i = 0; i < 4; ++i)
#pragma unroll
            for (int j = 0; j < NJ; ++j)
                acc[i][j] = __builtin_amdgcn_mfma_f32_16x16x32_bf16(a[i], b[j], acc[i][j], 0, 0, 0);
    }

    const long cz = (long)z * zsc;
#pragma unroll
    for (int i = 0; i < 4; ++i) {
        const int r0 = row0 + wr + i * 16 + (lane >> 4) * 4;
#pragma unroll
        for (int j = 0; j < NJ; ++j) {
            const int c = col0 + wc + j * 16 + m16;
            const float bv = BIAS ? bias[c] : 0.0f;
#pragma unroll
            for (int t = 0; t < 4; ++t) {
                const float x = acc[i][j][t] * alpha + bv;
                const long off = cz + (long)(r0 + t) * ldc + c;
                if (OBF16) ((short*)Cv)[off] = f2bf(x);
                else       ((float*)Cv)[off] = x;
            }
        }
    }
}

// ---------------- attention kernel A: softmax row sums ----------------
// single-buffered K staging (64 KiB LDS -> 2 blocks/CU)
__global__ __launch_bounds__(256) void attn_rowsum_k(
    const short* __restrict__ qkv,
    const float* __restrict__ cls_score, const float* __restrict__ fg_score,
    float* __restrict__ l_g)
{
    __shared__ short Qs[16384];
    __shared__ short Ks[16384];
    __shared__ float lsum[128][2];
    const int tid = threadIdx.x, wave = tid >> 6, lane = tid & 63;
    const int lrow = tid >> 2, lcol = (tid & 3) * 8;
    const int wr = (wave >> 1) * 64, wc = (wave & 1) * 64;
    const int m16 = lane & 15, q4 = lane >> 4, q8 = q4 * 8;
    const int row0 = blockIdx.x * 128, h = blockIdx.y, side = blockIdx.z;
    const float* sc_g = side ? fg_score : cls_score;
    const short* base = qkv + (long)side * PN * PC3 + h * PD;
    const short* Kg = base + PC;
    stage128(base + (long)row0 * PC3, PC3, Qs, wave, lrow, lcol);
    stage128(Kg, PC3, Ks, wave, lrow, lcol);
    __syncthreads();
    bf16x8 a[4][4];
#pragma unroll
    for (int i = 0; i < 4; ++i)
#pragma unroll
        for (int kc = 0; kc < 4; ++kc)
            a[i][kc] = *(const bf16x8*)&Qs[kc * 4096 + (wr + i * 16 + m16) * 32 + q8];
    float rs[4][4] = {};
    for (int ct = 0; ct < 16; ++ct) {
        if (ct) {
            __syncthreads();
            stage128(Kg + (long)ct * 128 * PC3, PC3, Ks, wave, lrow, lcol);
            __syncthreads();
        }
        f32x4 acc[4][4];
#pragma unroll
        for (int i = 0; i < 4; ++i)
#pragma unroll
            for (int j = 0; j < 4; ++j) acc[i][j] = (f32x4){0.f, 0.f, 0.f, 0.f};
#pragma unroll
        for (int kc = 0; kc < 4; ++kc) {
            bf16x8 b[4];
#pragma unroll
            for (int j = 0; j < 4; ++j)
                b[j] = *(const bf16x8*)&Ks[kc * 4096 + (wc + j * 16 + m16) * 32 + q8];
#pragma unroll
            for (int i = 0; i < 4; ++i)
#pragma unroll
                for (int j = 0; j < 4; ++j)
                    acc[i][j] = __builtin_amdgcn_mfma_f32_16x16x32_bf16(a[i][kc], b[j], acc[i][j], 0, 0, 0);
        }
#pragma unroll
        for (int j = 0; j < 4; ++j) {
            const float s25 = 25.0f * sc_g[ct * 128 + wc + j * 16 + m16];
#pragma unroll
            for (int i = 0; i < 4; ++i)
#pragma unroll
                for (int t = 0; t < 4; ++t)
                    rs[i][t] += __expf(acc[i][j][t] * s25);
        }
    }
#pragma unroll
    for (int i = 0; i < 4; ++i)
#pragma unroll
        for (int t = 0; t < 4; ++t) {
            float v = rs[i][t];
            v += __shfl_xor(v, 1, 64); v += __shfl_xor(v, 2, 64);
            v += __shfl_xor(v, 4, 64); v += __shfl_xor(v, 8, 64);
            if (m16 == 0) lsum[wr + i * 16 + q4 * 4 + t][wave & 1] = v;
        }
    __syncthreads();
    if (tid < 128)
        l_g[((long)side * PH + h) * PN + row0 + tid] = lsum[tid][0] + lsum[tid][1];
}

// ---------------- attention kernel B: attn tiles + sim_attn ----------------
// Transposed MFMA (swap A/B): lane holds 4 CONSECUTIVE COLUMNS -> vector stores.
// Single-buffered 64 KiB staging -> 2 blocks/CU.
__global__ __launch_bounds__(256) void attn_combine_k(
    const short* __restrict__ qkv,
    const float* __restrict__ cls_score, const float* __restrict__ fg_score,
    const float* __restrict__ l_g,
    short* __restrict__ attn8, float* __restrict__ sim_attn)
{
    __shared__ short Ts[32768];  // Q 16384 + K 16384 shorts = 64 KiB
    const int tid = threadIdx.x, wave = tid >> 6, lane = tid & 63;
    const int lrow = tid >> 2, lcol = (tid & 3) * 8;
    const int wr = (wave >> 1) * 64, wc = (wave & 1) * 64;
    const int m16 = lane & 15, q4 = lane >> 4, q8 = q4 * 8;
    const int col0 = blockIdx.x * 128, row0 = blockIdx.y * 128;
    const long NN = (long)PN * PN;

    f32x4 sim[4][4];
#pragma unroll
    for (int i = 0; i < 4; ++i)
#pragma unroll
        for (int j = 0; j < 4; ++j) sim[i][j] = (f32x4){0.f, 0.f, 0.f, 0.f};
    f32x4 comb[4][4];

    for (int st = 0; st < 16; ++st) {
        const int h = st >> 1, s = st & 1;
        const short* bq = qkv + (long)s * PN * PC3 + h * PD;
        __syncthreads();
        stage128(bq + (long)row0 * PC3, PC3, Ts, wave, lrow, lcol);        // Q rows
        stage128(bq + PC + (long)col0 * PC3, PC3, Ts + 16384, wave, lrow, lcol); // K rows
        __syncthreads();

        float rl[4];
#pragma unroll
        for (int j = 0; j < 4; ++j)
            rl[j] = 0.5f / l_g[((long)s * PH + h) * PN + row0 + wr + j * 16 + m16];

        // acc[i][j]: attn row = row0+wr+j*16+m16 ; col = col0+wc+i*16+q4*4+t
        f32x4 acc[4][4];
#pragma unroll
        for (int i = 0; i < 4; ++i)
#pragma unroll
            for (int j = 0; j < 4; ++j) acc[i][j] = (f32x4){0.f, 0.f, 0.f, 0.f};
#pragma unroll
        for (int kc = 0; kc < 4; ++kc) {
            bf16x8 kf[4], qf[4];
#pragma unroll
            for (int i = 0; i < 4; ++i)
                kf[i] = *(const bf16x8*)&Ts[16384 + kc * 4096 + (wc + i * 16 + m16) * 32 + q8];
#pragma unroll
            for (int j = 0; j < 4; ++j)
                qf[j] = *(const bf16x8*)&Ts[kc * 4096 + (wr + j * 16 + m16) * 32 + q8];
#pragma unroll
            for (int i = 0; i < 4; ++i)
#pragma unroll
                for (int j = 0; j < 4; ++j)
                    acc[i][j] = __builtin_amdgcn_mfma_f32_16x16x32_bf16(kf[i], qf[j], acc[i][j], 0, 0, 0);
        }
        const float* sc_g = s ? fg_score : cls_score;
#pragma unroll
        for (int i = 0; i < 4; ++i) {
            const f32x4 sc4 = *(const f32x4*)&sc_g[col0 + wc + i * 16 + q4 * 4];
#pragma unroll
            for (int j = 0; j < 4; ++j)
#pragma unroll
                for (int t = 0; t < 4; ++t) {
                    const float e = __expf(acc[i][j][t] * (25.0f * sc4[t])) * rl[j];
                    comb[i][j][t] = s ? (comb[i][j][t] + e) : e;
                }
        }
        if (s) {
#pragma unroll
            for (int j = 0; j < 4; ++j) {
                const long rb = (long)h * NN + (long)(row0 + wr + j * 16 + m16) * PN
                              + col0 + wc + q4 * 4;
#pragma unroll
                for (int i = 0; i < 4; ++i) {
                    s4v o;
#pragma unroll
                    for (int t = 0; t < 4; ++t) o[t] = f2bf(comb[i][j][t]);
                    *(s4v*)&attn8[rb + i * 16] = o;
                    sim[i][j] += comb[i][j] * 0.125f;
                }
            }
        }
    }
#pragma unroll
    for (int j = 0; j < 4; ++j) {
        const long rb = (long)(row0 + wr + j * 16 + m16) * PN + col0 + wc + q4 * 4;
#pragma unroll
        for (int i = 0; i < 4; ++i)
            *(f32x4*)&sim_attn[rb + i * 16] = sim[i][j];
    }
}

// ---------------- fused fp32 -> bf16 convert (6 segments, contiguous dst) ----------------
// total float4s = 512K+512K+768K+768K+1024K+1024K = 4,718,592  -> 18432 blocks x 256
__global__ __launch_bounds__(256) void f2bf6_k(
    const float* __restrict__ s0, const float* __restrict__ s1,
    const float* __restrict__ s2, const float* __restrict__ s3,
    const float* __restrict__ s4, const float* __restrict__ s5,
    short* __restrict__ dst)
{
    const int n0 = 512 * 1024, n1 = 512 * 1024, n2 = 768 * 1024,
              n3 = 768 * 1024, n4 = 1024 * 1024;
    const int i = blockIdx.x * 256 + threadIdx.x;
    const float* src;
    int j = i;
    if (j < n0) src = s0;
    else { j -= n0; if (j < n1) src = s1;
    else { j -= n1; if (j < n2) src = s2;
    else { j -= n2; if (j < n3) src = s3;
    else { j -= n3; if (j < n4) src = s4;
    else { j -= n4; src = s5; } } } } }
    float4 v = ((const float4*)src)[j];
    s4v o;
    o[0] = f2bf(v.x); o[1] = f2bf(v.y); o[2] = f2bf(v.z); o[3] = f2bf(v.w);
    ((s4v*)dst)[i] = o;
}

// ---------------- bf16 tiled transpose ----------------
__global__ __launch_bounds__(256) void transpose_bf16_k(
    const short* __restrict__ src, int sld, short* __restrict__ dst, int dld)
{
    __shared__ short tl[64][72];
    const int r0 = blockIdx.y * 64, c0 = blockIdx.x * 64;
    const int tr = threadIdx.x >> 2;
    const int tc = (threadIdx.x & 3) * 16;
    const short* sp = src + (long)(r0 + tr) * sld + c0 + tc;
    s8v v0 = *(const s8v*)sp;
    s8v v1 = *(const s8v*)(sp + 8);
    *(s8v*)&tl[tr][tc] = v0;
    *(s8v*)&tl[tr][tc + 8] = v1;
    __syncthreads();
    s8v o0, o1;
#pragma unroll
    for (int k = 0; k < 8; ++k) { o0[k] = tl[tc + k][tr]; o1[k] = tl[tc + 8 + k][tr]; }
    short* dp = dst + (long)(c0 + tr) * dld + r0 + tc;
    *(s8v*)dp = o0;
    *(s8v*)(dp + 8) = o1;
}

// ---------------- merged L2 norms: y=0..3 -> {cls,reg}x{q,k}; y=4 -> v path ----------------
__global__ __launch_bounds__(256) void norms_k(short* __restrict__ qkv,
                                               short* __restrict__ Vn,
                                               short* __restrict__ trans)
{
    const int n = blockIdx.x, which = blockIdx.y, t = threadIdx.x;
    if (which < 4) {
        short* p = qkv + (long)(which >> 1) * ((long)PN * PC3)
                 + (long)n * PC3 + (which & 1) * PC + t * 4;
        s4v v = *(s4v*)p;
        float f0 = bf2f(v[0]), f1 = bf2f(v[1]), f2 = bf2f(v[2]), f3 = bf2f(v[3]);
        float ss = f0 * f0 + f1 * f1 + f2 * f2 + f3 * f3;
        ss += __shfl_xor(ss, 16, 64); ss += __shfl_xor(ss, 8, 64);
        ss += __shfl_xor(ss, 4, 64);  ss += __shfl_xor(ss, 2, 64);
        ss += __shfl_xor(ss, 1, 64);
        const float rn = rsqrtf(ss);
        s4v o;
        o[0] = f2bf(f0 * rn); o[1] = f2bf(f1 * rn);
        o[2] = f2bf(f2 * rn); o[3] = f2bf(f3 * rn);
        *(s4v*)p = o;
    } else {
        const short* p = qkv + (long)n * PC3 + 2 * PC + t * 4;
        s4v v = *(const s4v*)p;
        float f0 = bf2f(v[0]), f1 = bf2f(v[1]), f2 = bf2f(v[2]), f3 = bf2f(v[3]);
        float ss = f0 * f0 + f1 * f1 + f2 * f2 + f3 * f3;
        ss += __shfl_xor(ss, 16, 64); ss += __shfl_xor(ss, 8, 64);
        ss += __shfl_xor(ss, 4, 64);  ss += __shfl_xor(ss, 2, 64);
        ss += __shfl_xor(ss, 1, 64);
        const float rn = rsqrtf(ss);
        s4v o;
        o[0] = f2bf(f0 * rn); o[1] = f2bf(f1 * rn);
        o[2] = f2bf(f2 * rn); o[3] = f2bf(f3 * rn);
        *(s4v*)(Vn + (long)n * PC + t * 4) = o;
        *(s4v*)(trans + (long)n * (2 * PC) + PC + t * 4) = v;
    }
}

// ---------------- reductions ----------------
__device__ __forceinline__ float wave_sum(float v) {
#pragma unroll
    for (int o = 32; o > 0; o >>= 1) v += __shfl_xor(v, o, 64);
    return v;
}
__device__ __forceinline__ float wave_max(float v) {
#pragma unroll
    for (int o = 32; o > 0; o >>= 1) v = fmaxf(v, __shfl_xor(v, o, 64));
    return v;
}
__device__ __forceinline__ float block_sum(float v, float* sm) {
    v = wave_sum(v);
    __syncthreads();
    if ((threadIdx.x & 63) == 0) sm[threadIdx.x >> 6] = v;
    __syncthreads();
    return sm[0] + sm[1] + sm[2] + sm[3];
}
__device__ __forceinline__ float block_max(float v, float* sm) {
    v = wave_max(v);
    __syncthreads();
    if ((threadIdx.x & 63) == 0) sm[threadIdx.x >> 6] = v;
    __syncthreads();
    return fmaxf(fmaxf(sm[0], sm[1]), fmaxf(sm[2], sm[3]));
}

// ---------------- sim_round2 ----------------
__global__ __launch_bounds__(256) void sim_round2_k(
    const float* __restrict__ S, const short* __restrict__ Sraw,
    short* __restrict__ Sout)
{
    __shared__ float sm[4];
    const long row = (long)blockIdx.x * PN;
    const int t = threadIdx.x;
    float v[8];
    bool keep[8];
#pragma unroll
    for (int j = 0; j < 8; ++j) {
        const int m = t + 256 * j;
        v[j] = S[row + m];
        keep[j] = bf2f(Sraw[row + m]) > 0.75f;
    }
    float mx = -1e30f;
#pragma unroll
    for (int j = 0; j < 8; ++j) mx = fmaxf(mx, v[j]);
    mx = block_max(mx, sm);
    float sum = 0.f;
#pragma unroll
    for (int j = 0; j < 8; ++j) { v[j] = __expf(v[j] - mx); sum += v[j]; }
    sum = block_sum(sum, sm);
    const float inv = 1.0f / sum;
    float msum = 0.f;
#pragma unroll
    for (int j = 0; j < 8; ++j) { v[j] = keep[j] ? v[j] * inv : 0.f; msum += v[j]; }
    msum = block_sum(msum, sm);
    const float minv = 1.0f / msum;
#pragma unroll
    for (int j = 0; j < 8; ++j) {
        const int m = t + 256 * j;
        Sout[row + m] = f2bf(v[j] * minv);
    }
}

// ---------------- host ----------------
extern "C" void kernel_launch(void* const* d_in, const int* in_sizes, int n_in,
                              void* d_out, int out_size, void* d_ws, size_t ws_size,
                              hipStream_t stream)
{
    (void)in_sizes; (void)n_in; (void)out_size; (void)ws_size;
    const float* x_cls = (const float*)d_in[0];
    const float* x_reg = (const float*)d_in[1];
    const float* cls_score = (const float*)d_in[2];
    const float* fg_score = (const float*)d_in[3];
    const float* Wqc = (const float*)d_in[4];
    const float* Wqr = (const float*)d_in[5];
    const float* W1 = (const float*)d_in[6];
    const float* b1 = (const float*)d_in[7];
    const float* W2 = (const float*)d_in[8];
    const float* b2 = (const float*)d_in[9];
    float* out = (float*)d_out;

    // ---- workspace (MiB offsets), peak ~156.2 MiB ----
    char* w = (char*)d_ws;
    short* qkv_cls_bf = (short*)(w + ((size_t)0   << 20)); // 12 MiB [N,3C]
    short* qkv_reg_bf = (short*)(w + ((size_t)12  << 20)); // 12 MiB (adjacent)
    short* attn8      = (short*)(w + ((size_t)24  << 20)); // 64 MiB [8][N][N] bf16
    float* sim_attn   = (float*)(w + ((size_t)88  << 20)); // 16 MiB
    short* sim_raw_bf = (short*)(w + ((size_t)104 << 20)); // 8 MiB
    short* Vn         = (short*)(w + ((size_t)112 << 20)); // 4 MiB
    short* vT         = (short*)(w + ((size_t)116 << 20)); // 4 MiB [C,N]
    short* bf_all     = (short*)(w + ((size_t)120 << 20)); // 36 MiB contiguous:
    short* x_cls_bf   = bf_all;                            //  @120, 4 MiB
    short* x_reg_bf   = (short*)(w + ((size_t)124 << 20)); //  4 MiB
    short* Wqc_bf     = (short*)(w + ((size_t)128 << 20)); //  6 MiB
    short* Wqr_bf     = (short*)(w + ((size_t)134 << 20)); //  6 MiB
    short* W1_bf      = (short*)(w + ((size_t)140 << 20)); //  8 MiB
    short* W2_bf      = (short*)(w + ((size_t)148 << 20)); //  8 MiB (ends 156)
    float* l_g        = (float*)(w + ((size_t)156 << 20)); // 128 KiB [2][8][N]
    // overlays (written only after their underlying buffers are dead):
    short* trans      = (short*)(w + ((size_t)120 << 20)); // 8 MiB over x_* (post-QKV)
    short* sim_bf     = (short*)(w + ((size_t)24  << 20)); // 8 MiB over attn8[0] (post attn@V)
    short* featT      = (short*)(w + ((size_t)32  << 20)); // 8 MiB over attn8[1]
    short* ave        = (short*)(w + ((size_t)40  << 20)); // 16 MiB over attn8[2..3]

    const long NN = (long)PN * PN;

    // ---- fused fp32 -> bf16 (one launch; dst = bf_all contiguous) ----
    f2bf6_k<<<18432, 256, 0, stream>>>(x_cls, x_reg, Wqc, Wqr, W1, W2, bf_all);

    // ---- QKV projections ----
    mfma_gemm_k<128, true, false><<<dim3(24, 16, 1), 256, 0, stream>>>(
        x_cls_bf, PC, 0, Wqc_bf, PC, 0, qkv_cls_bf, PC3, 0, PC, 1.0f, nullptr);
    mfma_gemm_k<128, true, false><<<dim3(16, 16, 1), 256, 0, stream>>>(  // q,k only
        x_reg_bf, PC, 0, Wqr_bf, PC, 0, qkv_reg_bf, PC3, 0, PC, 1.0f, nullptr);

    // ---- all norms in one launch; v transpose ----
    norms_k<<<dim3(PN, 5), 256, 0, stream>>>(qkv_cls_bf, Vn, trans);
    transpose_bf16_k<<<dim3(PC / 64, PN / 64), 256, 0, stream>>>(
        qkv_cls_bf + 2 * PC, PC3, vT, PN);

    // ---- sim_raw = (Vn @ Vn^T)/H, one K=1024 GEMM ----
    mfma_gemm_k<128, true, false><<<dim3(16, 16, 1), 256, 0, stream>>>(
        Vn, PC, 0, Vn, PC, 0, sim_raw_bf, PN, 0, PC, 0.125f, nullptr);

    // ---- fused attention: row sums, then attn+sim tiles ----
    attn_rowsum_k<<<dim3(16, PH, 2), 256, 0, stream>>>(
        qkv_cls_bf, cls_score, fg_score, l_g);
    attn_combine_k<<<dim3(16, 16), 256, 0, stream>>>(
        qkv_cls_bf, cls_score, fg_score, l_g, attn8, sim_attn);

    // ---- x = attn @ v, all 8 heads z-batched ----
    mfma_gemm_k<64, true, false><<<dim3(2, 16, PH), 256, 0, stream>>>(
        attn8, PN, NN, vT, PN, (long)PD * PN, trans, 2 * PC, PD, PN, 1.0f, nullptr);

    // ---- sim_round2 ----
    sim_round2_k<<<PN, 256, 0, stream>>>(sim_attn, sim_raw_bf, sim_bf);

    // ---- msa/feat = trans @ W1^T + b1 -> ave cols [2C,4C) ----
    mfma_gemm_k<128, true, true><<<dim3(16, 16, 1), 256, 0, stream>>>(
        trans, 2 * PC, 0, W1_bf, 2 * PC, 0, ave + 2 * PC, 4 * PC, 0, 2 * PC, 1.0f, b1);

    // ---- featT = feat^T ----
    transpose_bf16_k<<<dim3(32, 32), 256, 0, stream>>>(ave + 2 * PC, 4 * PC, featT, 2 * PC);

    // ---- soft_sim = sim_round2 @ feat -> ave cols [0,2C) ----
    mfma_gemm_k<128, true, false><<<dim3(16, 16, 1), 256, 0, stream>>>(
        sim_bf, 2 * PC, 0, featT, 2 * PC, 0, ave, 4 * PC, 0, 2 * PC, 1.0f, nullptr);

    // ---- out = ave @ W2^T + b2 ----
    mfma_gemm_k<64, false, true><<<dim3(16, 16, 1), 256, 0, stream>>>(
        ave, 4 * PC, 0, W2_bf, 4 * PC, 0, out, PC, 0, 4 * PC, 1.0f, b2);
}